// Round 6
// baseline (17.186 us; speedup 1.0000x reference)
//
#include <hip/hip_runtime.h>

#define NB 4096
#define TPB 1024
#define WPB (TPB / 64)        // 16 waves (bodies) per block
#define NBLK (NB / WPB)       // 256 blocks
#define NPAIR (NB / 2)        // 2048 packed source-pairs
#define NT (NPAIR / 64)       // 32 iterations per lane (2 sources each)

// R4 kernel + slope probe: main loop executed TWICE (second pass with
// asm-laundered inputs so it can't be CSE'd), results averaged -> bitwise
// identical output, dur_us delta vs R4 == true main-loop execution time.
__global__ __launch_bounds__(TPB) void nbody_wave(
    const float* __restrict__ x, const float* __restrict__ m,
    float4* __restrict__ out)
{
    __shared__ float4 qp[NPAIR];  // 32 KB
    __shared__ float2 mp[NPAIR];  // 16 KB

    const int tid = threadIdx.x;

    #pragma unroll
    for (int t = 0; t < NPAIR / TPB; ++t) {
        const int j = t * TPB + tid;
        const float4 a = ((const float4*)x)[2 * j];
        const float4 b = ((const float4*)x)[2 * j + 1];
        qp[j] = make_float4(a.x, a.y, b.x, b.y);
        mp[j] = ((const float2*)m)[j];
    }
    __syncthreads();

    const int wave = tid >> 6;
    const int lane = tid & 63;
    const int k = blockIdx.x * WPB + wave;

    const float4 xk = ((const float4*)x)[k];
    const float qx = xk.x, qy = xk.y;

    // ---- pass 1 ----
    float ax = 0.f, ay = 0.f;
    #pragma unroll 8
    for (int t = 0; t < NT; ++t) {
        const int p = t * 64 + lane;
        const float4 q = qp[p];
        const float2 mm = mp[p];
        {
            const float dx = qx - q.x;
            const float dy = qy - q.y;
            const float sq = fmaf(dx, dx, fmaf(dy, dy, 1e-20f));
            const float r = __builtin_amdgcn_rsqf(sq);
            const float w = r * r * r * mm.x;
            ax = fmaf(dx, w, ax);
            ay = fmaf(dy, w, ay);
        }
        {
            const float dx = qx - q.z;
            const float dy = qy - q.w;
            const float sq = fmaf(dx, dx, fmaf(dy, dy, 1e-20f));
            const float r = __builtin_amdgcn_rsqf(sq);
            const float w = r * r * r * mm.y;
            ax = fmaf(dx, w, ax);
            ay = fmaf(dy, w, ay);
        }
    }

    // ---- pass 2: identical math on laundered inputs (no CSE possible) ----
    float qx2 = qx, qy2 = qy;
    asm volatile("" : "+v"(qx2), "+v"(qy2));   // opaque to the optimizer
    float ax2 = 0.f, ay2 = 0.f;
    #pragma unroll 8
    for (int t = 0; t < NT; ++t) {
        const int p = t * 64 + lane;
        const float4 q = qp[p];
        const float2 mm = mp[p];
        {
            const float dx = qx2 - q.x;
            const float dy = qy2 - q.y;
            const float sq = fmaf(dx, dx, fmaf(dy, dy, 1e-20f));
            const float r = __builtin_amdgcn_rsqf(sq);
            const float w = r * r * r * mm.x;
            ax2 = fmaf(dx, w, ax2);
            ay2 = fmaf(dy, w, ay2);
        }
        {
            const float dx = qx2 - q.z;
            const float dy = qy2 - q.w;
            const float sq = fmaf(dx, dx, fmaf(dy, dy, 1e-20f));
            const float r = __builtin_amdgcn_rsqf(sq);
            const float w = r * r * r * mm.y;
            ax2 = fmaf(dx, w, ax2);
            ay2 = fmaf(dy, w, ay2);
        }
    }

    // ax2 is bitwise == ax, so (ax+ax2)*0.5 == ax exactly.
    ax = (ax + ax2) * 0.5f;
    ay = (ay + ay2) * 0.5f;

    // Adjacent-pair extra weight (tril diagonal=1 double-count), lanes 0/1.
    int nbi = -1;
    if (lane == 0 && k > 0) nbi = k - 1;
    else if (lane == 1 && k < NB - 1) nbi = k + 1;
    if (nbi >= 0) {
        const float4 q = qp[nbi >> 1];
        const float2 mm = mp[nbi >> 1];
        const float sx = (nbi & 1) ? q.z : q.x;
        const float sy = (nbi & 1) ? q.w : q.y;
        const float sm = (nbi & 1) ? mm.y : mm.x;
        const float dx = qx - sx;
        const float dy = qy - sy;
        const float sq = fmaf(dx, dx, dy * dy);
        const float r = __builtin_amdgcn_rsqf(sq);
        const float w = r * r * r * sm;
        ax = fmaf(dx, w, ax);
        ay = fmaf(dy, w, ay);
    }

    #pragma unroll
    for (int off = 32; off > 0; off >>= 1) {
        ax += __shfl_xor(ax, off);
        ay += __shfl_xor(ay, off);
    }

    if (lane == 0) {
        const float m0inv = 1.0f / m[0];
        out[k] = make_float4(xk.z * m0inv, xk.w * m0inv, ax * m[k], ay * m[k]);
    }
}

extern "C" void kernel_launch(void* const* d_in, const int* in_sizes, int n_in,
                              void* d_out, int out_size, void* d_ws, size_t ws_size,
                              hipStream_t stream) {
    const float* x = (const float*)d_in[0];
    const float* m = (const float*)d_in[1];
    nbody_wave<<<dim3(NBLK), dim3(TPB), 0, stream>>>(x, m, (float4*)d_out);
}

// Round 7
// 12.458 us; speedup vs baseline: 1.3795x; 1.3795x over previous
//
#include <hip/hip_runtime.h>

#define NB 4096
#define TPB 256
#define U 4                    // bodies per wave (held in registers)
#define NBLK (NB / (U * (TPB / 64)))   // 256 blocks, 1 per CU
#define NT (NB / 64)           // 64 source iterations per lane

// Wave W owns bodies 4W..4W+3 in registers; its 64 lanes split the sources
// (lane l: j = 64t + l). One ds_read_b128 of (qx,qy,m,pad) feeds 4 pairs ->
// LDS traffic 4 B/pair (was 12). Intra-wave butterfly reduce; no cross-wave
// or cross-block communication. Self-pair killed by the 1e-20 bias.
__global__ __launch_bounds__(TPB) void nbody_u4(
    const float* __restrict__ x, const float* __restrict__ m,
    float4* __restrict__ out)
{
    __shared__ float4 qm[NB];          // 64 KB: (qx, qy, m, 0)

    const int tid = threadIdx.x;

    #pragma unroll
    for (int t = 0; t < NB / TPB; ++t) {    // 16 iters, coalesced
        const int j = t * TPB + tid;
        const float4 xj = ((const float4*)x)[j];
        qm[j] = make_float4(xj.x, xj.y, m[j], 0.f);
    }
    __syncthreads();

    const int lane = tid & 63;
    const int W = blockIdx.x * (TPB / 64) + (tid >> 6);
    const int kb = U * W;                   // first body of this wave

    // Wave-uniform body loads -> scalar pipe.
    const float4 xk0 = ((const float4*)x)[kb + 0];
    const float4 xk1 = ((const float4*)x)[kb + 1];
    const float4 xk2 = ((const float4*)x)[kb + 2];
    const float4 xk3 = ((const float4*)x)[kb + 3];

    float ax0 = 0.f, ay0 = 0.f, ax1 = 0.f, ay1 = 0.f;
    float ax2 = 0.f, ay2 = 0.f, ax3 = 0.f, ay3 = 0.f;

    #pragma unroll 8
    for (int t = 0; t < NT; ++t) {
        const int j = t * 64 + lane;
        const float4 s = qm[j];             // one b128 serves 4 pairs
        {
            const float dx = xk0.x - s.x, dy = xk0.y - s.y;
            const float sq = fmaf(dx, dx, fmaf(dy, dy, 1e-20f));
            const float r = __builtin_amdgcn_rsqf(sq);
            const float w = r * r * r * s.z;
            ax0 = fmaf(dx, w, ax0); ay0 = fmaf(dy, w, ay0);
        }
        {
            const float dx = xk1.x - s.x, dy = xk1.y - s.y;
            const float sq = fmaf(dx, dx, fmaf(dy, dy, 1e-20f));
            const float r = __builtin_amdgcn_rsqf(sq);
            const float w = r * r * r * s.z;
            ax1 = fmaf(dx, w, ax1); ay1 = fmaf(dy, w, ay1);
        }
        {
            const float dx = xk2.x - s.x, dy = xk2.y - s.y;
            const float sq = fmaf(dx, dx, fmaf(dy, dy, 1e-20f));
            const float r = __builtin_amdgcn_rsqf(sq);
            const float w = r * r * r * s.z;
            ax2 = fmaf(dx, w, ax2); ay2 = fmaf(dy, w, ay2);
        }
        {
            const float dx = xk3.x - s.x, dy = xk3.y - s.y;
            const float sq = fmaf(dx, dx, fmaf(dy, dy, 1e-20f));
            const float r = __builtin_amdgcn_rsqf(sq);
            const float w = r * r * r * s.z;
            ax3 = fmaf(dx, w, ax3); ay3 = fmaf(dy, w, ay3);
        }
    }

    // Adjacent pairs |k-j|==1 weigh 2 under tril(.,diagonal=1); main loop
    // counted them once. Lanes 0..7: body = lane>>1, neighbor = k +/- 1.
    {
        const int body = lane >> 1;
        const int k = kb + body;
        const int nb = (lane & 1) ? k + 1 : k - 1;
        float cx = 0.f, cy = 0.f;
        if (lane < 8 && nb >= 0 && nb < NB) {
            const float qx = (body == 0) ? xk0.x : (body == 1) ? xk1.x
                           : (body == 2) ? xk2.x : xk3.x;
            const float qy = (body == 0) ? xk0.y : (body == 1) ? xk1.y
                           : (body == 2) ? xk2.y : xk3.y;
            const float4 s = qm[nb];
            const float dx = qx - s.x, dy = qy - s.y;
            const float sq = fmaf(dx, dx, dy * dy);
            const float r = __builtin_amdgcn_rsqf(sq);
            const float w = r * r * r * s.z;
            cx = dx * w; cy = dy * w;
        }
        ax0 += (body == 0) ? cx : 0.f;  ay0 += (body == 0) ? cy : 0.f;
        ax1 += (body == 1) ? cx : 0.f;  ay1 += (body == 1) ? cy : 0.f;
        ax2 += (body == 2) ? cx : 0.f;  ay2 += (body == 2) ? cy : 0.f;
        ax3 += (body == 3) ? cx : 0.f;  ay3 += (body == 3) ? cy : 0.f;
    }

    // Wave butterfly reduction (fixed order -> deterministic).
    #pragma unroll
    for (int off = 32; off > 0; off >>= 1) {
        ax0 += __shfl_xor(ax0, off);  ay0 += __shfl_xor(ay0, off);
        ax1 += __shfl_xor(ax1, off);  ay1 += __shfl_xor(ay1, off);
        ax2 += __shfl_xor(ax2, off);  ay2 += __shfl_xor(ay2, off);
        ax3 += __shfl_xor(ax3, off);  ay3 += __shfl_xor(ay3, off);
    }

    if (lane < U) {
        const int k = kb + lane;
        const float4 xk = (lane == 0) ? xk0 : (lane == 1) ? xk1
                        : (lane == 2) ? xk2 : xk3;
        const float sx = (lane == 0) ? ax0 : (lane == 1) ? ax1
                       : (lane == 2) ? ax2 : ax3;
        const float sy = (lane == 0) ? ay0 : (lane == 1) ? ay1
                       : (lane == 2) ? ay2 : ay3;
        const float m0inv = 1.0f / m[0];
        out[k] = make_float4(xk.z * m0inv, xk.w * m0inv, sx * m[k], sy * m[k]);
    }
}

extern "C" void kernel_launch(void* const* d_in, const int* in_sizes, int n_in,
                              void* d_out, int out_size, void* d_ws, size_t ws_size,
                              hipStream_t stream) {
    const float* x = (const float*)d_in[0];
    const float* m = (const float*)d_in[1];
    nbody_u4<<<dim3(NBLK), dim3(TPB), 0, stream>>>(x, m, (float4*)d_out);
}

// Round 9
// 11.835 us; speedup vs baseline: 1.4521x; 1.0527x over previous
//
#include <hip/hip_runtime.h>

typedef float v2f __attribute__((ext_vector_type(2)));
typedef float v4f __attribute__((ext_vector_type(4)));

#define NB 4096
#define TPB 1024
#define WPB 16                 // waves per block (1 body per wave)
#define NBLK (NB / WPB)        // 256 blocks
#define NPAIR (NB / 2)         // 2048 packed source-pairs
#define NT (NPAIR / 64)        // 32 inner iterations per lane (2 sources each)

// One wave per body k; lane l handles source-pair p = 64t + l (sources 2p,2p+1)
// as <2 x float> vector ops (compiler selects v_pk_*_f32 on gfx950; falls back
// to scalar pairs with identical semantics). Self-pair killed by 1e-20 bias.
__global__ __launch_bounds__(TPB) void nbody_vec(
    const float* __restrict__ x, const float* __restrict__ m,
    float4* __restrict__ out)
{
    __shared__ v4f qq[NPAIR];     // 32 KB: (x0, x1, y0, y1)
    __shared__ v2f mp[NPAIR];     // 16 KB: (m0, m1)

    const int tid = threadIdx.x;

    #pragma unroll
    for (int t = 0; t < NPAIR / TPB; ++t) {   // 2 iters, coalesced
        const int p = t * TPB + tid;
        const float4 a = ((const float4*)x)[2 * p];
        const float4 b = ((const float4*)x)[2 * p + 1];
        v4f v = {a.x, b.x, a.y, b.y};
        qq[p] = v;
        const float2 mmv = ((const float2*)m)[p];
        v2f mv = {mmv.x, mmv.y};
        mp[p] = mv;
    }
    __syncthreads();

    const int wave = tid >> 6;
    const int lane = tid & 63;
    const int k = blockIdx.x * WPB + wave;

    const float4 xk = ((const float4*)x)[k];  // wave-uniform -> scalar load
    const v2f qxx = {xk.x, xk.x};
    const v2f qyy = {xk.y, xk.y};
    const v2f eps2 = {1e-20f, 1e-20f};
    v2f accx = {0.f, 0.f}, accy = {0.f, 0.f};

    #pragma unroll 8
    for (int t = 0; t < NT; ++t) {
        const int p = t * 64 + lane;
        const v4f s = qq[p];                  // ds_read_b128
        const v2f mm = mp[p];                 // ds_read_b64
        const v2f dxs = qxx - s.lo;           // (qx-x0, qx-x1)
        const v2f dys = qyy - s.hi;           // (qy-y0, qy-y1)
        v2f sq = __builtin_elementwise_fma(dys, dys, eps2);
        sq = __builtin_elementwise_fma(dxs, dxs, sq);
        v2f r;
        r.x = __builtin_amdgcn_rsqf(sq.x);
        r.y = __builtin_amdgcn_rsqf(sq.y);
        const v2f w = r * r * r * mm;
        accx = __builtin_elementwise_fma(dxs, w, accx);
        accy = __builtin_elementwise_fma(dys, w, accy);
    }

    float ax = accx.x + accx.y;
    float ay = accy.x + accy.y;

    // Adjacent pairs |k-i|==1 weigh 2 under tril(.,diagonal=1); the main loop
    // counted them once. Lanes 0/1 add the extra unit weight.
    int nbi = -1;
    if (lane == 0 && k > 0) nbi = k - 1;
    else if (lane == 1 && k < NB - 1) nbi = k + 1;
    if (nbi >= 0) {
        const v4f s = qq[nbi >> 1];
        const v2f mm = mp[nbi >> 1];
        const float sx = (nbi & 1) ? s.y : s.x;
        const float sy = (nbi & 1) ? s.w : s.z;
        const float sm = (nbi & 1) ? mm.y : mm.x;
        const float dx = xk.x - sx;
        const float dy = xk.y - sy;
        const float sqn = fmaf(dx, dx, dy * dy);
        const float r = __builtin_amdgcn_rsqf(sqn);
        const float w = r * r * r * sm;
        ax = fmaf(dx, w, ax);
        ay = fmaf(dy, w, ay);
    }

    // Wave butterfly reduction (fixed order -> deterministic).
    #pragma unroll
    for (int off = 32; off > 0; off >>= 1) {
        ax += __shfl_xor(ax, off);
        ay += __shfl_xor(ay, off);
    }

    if (lane == 0) {
        const float m0inv = 1.0f / m[0];
        out[k] = make_float4(xk.z * m0inv, xk.w * m0inv, ax * m[k], ay * m[k]);
    }
}

extern "C" void kernel_launch(void* const* d_in, const int* in_sizes, int n_in,
                              void* d_out, int out_size, void* d_ws, size_t ws_size,
                              hipStream_t stream) {
    const float* x = (const float*)d_in[0];
    const float* m = (const float*)d_in[1];
    nbody_vec<<<dim3(NBLK), dim3(TPB), 0, stream>>>(x, m, (float4*)d_out);
}